// Round 8
// baseline (694.283 us; speedup 1.0000x reference)
//
#include <hip/hip_runtime.h>

#define HID    128
#define GATES  512      // 4*HID
#define EMB    64
#define TSTEPS 1024
#define BATCH  512
#define VOCAB  50257
#define NCLS   28
#define HSTRIDE 160     // h row stride in shorts: 320B = 16 banks mod 32
#define TPAD   8        // token row pad (ints) -> rows land on different banks

typedef __attribute__((ext_vector_type(8))) short short8;   // 8 bf16 = 4 VGPRs
typedef __attribute__((ext_vector_type(4))) float f32x4;

// lgkm-only barrier: LDS visibility without draining global (vmcnt) loads.
#define BAR_LGKM() __asm__ __volatile__("s_waitcnt lgkmcnt(0)\n\ts_barrier" ::: "memory")

static __device__ __forceinline__ float bf2f(unsigned short u){
  union { unsigned int i; float f; } v; v.i = ((unsigned int)u) << 16; return v.f;
}
static __device__ __forceinline__ unsigned short f2bf(float f){
  union { float ff; unsigned int i; } v; v.ff = f;
  unsigned int x = v.i;
  x += 0x7fffu + ((x >> 16) & 1u);   // round-to-nearest-even
  return (unsigned short)(x >> 16);
}
static __device__ __forceinline__ float sigf(float x){
  float e = __builtin_amdgcn_exp2f(-1.44269504f * x);
  return __builtin_amdgcn_rcpf(1.f + e);
}
static __device__ __forceinline__ float tanhf_fast(float x){
  float xx = fminf(fmaxf(x, -16.f), 16.f);
  float e = __builtin_amdgcn_exp2f(-2.88539008f * xx);   // exp(-2x)
  return (1.f - e) * __builtin_amdgcn_rcpf(1.f + e);
}

// ---------------------------------------------------------------------------
// Phase 1: proj[v][g] = sum_e emb[v][e]*w_ih[g][e] + b_ih[g] + b_hh[g]
// f32 inputs; split-bf16 (hi+lo) MFMA -> f32-accurate. Unchanged (verified).
// ---------------------------------------------------------------------------
template<bool STORE_F32>
__global__ __launch_bounds__(256) void emb_proj_kernel(
    const float* __restrict__ emb,     // [V][64]
    const float* __restrict__ w_ih,    // [512][64]
    const float* __restrict__ b_ih,    // [512]
    const float* __restrict__ b_hh,    // [512]
    void* __restrict__ proj_raw)       // [V][512] f32 or bf16
{
  int wave = threadIdx.x >> 6;
  int lane = threadIdx.x & 63;
  int n = lane & 15;
  int q = lane >> 4;
  long v0 = (long)blockIdx.x * 16;

  long vrow = v0 + n; if (vrow >= VOCAB) vrow = VOCAB - 1;
  const float* er = emb + vrow * EMB;
  short8 ahi[2], alo[2];
  #pragma unroll
  for (int ch = 0; ch < 2; ++ch){
    #pragma unroll
    for (int j = 0; j < 8; ++j){
      float xv = er[ch * 32 + q * 8 + j];
      unsigned short h = f2bf(xv);
      float r = xv - bf2f(h);
      ahi[ch][j] = (short)h;
      alo[ch][j] = (short)f2bf(r);
    }
  }

  #pragma unroll
  for (int i = 0; i < 8; ++i){
    int g0 = (wave * 8 + i) * 16;
    const float* wr = w_ih + (long)(g0 + n) * EMB;
    short8 bhi[2], blo[2];
    #pragma unroll
    for (int ch = 0; ch < 2; ++ch){
      #pragma unroll
      for (int j = 0; j < 8; ++j){
        float xv = wr[ch * 32 + q * 8 + j];
        unsigned short h = f2bf(xv);
        float r = xv - bf2f(h);
        bhi[ch][j] = (short)h;
        blo[ch][j] = (short)f2bf(r);
      }
    }
    float bias = b_ih[g0 + n] + b_hh[g0 + n];
    f32x4 acc = {bias, bias, bias, bias};
    #pragma unroll
    for (int ch = 0; ch < 2; ++ch){
      acc = __builtin_amdgcn_mfma_f32_16x16x32_bf16(ahi[ch], bhi[ch], acc, 0, 0, 0);
      acc = __builtin_amdgcn_mfma_f32_16x16x32_bf16(ahi[ch], blo[ch], acc, 0, 0, 0);
      acc = __builtin_amdgcn_mfma_f32_16x16x32_bf16(alo[ch], bhi[ch], acc, 0, 0, 0);
    }
    #pragma unroll
    for (int r = 0; r < 4; ++r){
      long row = v0 + q * 4 + r;
      if (row < VOCAB){
        if (STORE_F32)
          ((float*)proj_raw)[row * GATES + g0 + n] = acc[r];
        else
          ((unsigned short*)proj_raw)[row * GATES + g0 + n] = f2bf(acc[r]);
      }
    }
  }
}

// ---------------------------------------------------------------------------
// Phase 2: LSTM recurrence + final linear.
// 256 blocks x 256 threads (4 waves), R=2 rows/block, 1 wave/SIMD.
// Wave w owns hcols [w*32, w*32+32) as tiles (t, s in {0,1}).
// A packs batch row0 at A-rows 0-3/8-11, row1 at 4-7/12-15 (arow=(n>>2)&1):
// C rows 0,4 hold real gates and rows 8,12 hold FREE DUPLICATES ->
// cell(lane) = (row=q&1, hcol=w*32+(q>>1)*16+n) lives in acc[t][q>>1].reg0:
// ALL 64 lanes own exactly one cell, in-register nonlinearity, 10 trans/wave
// covering 64 cells (per-SIMD trans issue halved vs 8-wave version).
// 32 MFMA/wave = 8 independent chains x depth 4. One lgkm-only barrier/step;
// depth-2 gx prefetch, exactly 4 gather loads per lane (no redundancy).
// ---------------------------------------------------------------------------
template<bool GXF32>
__global__ __launch_bounds__(256, 1) void lstm_kernel(
    const int* __restrict__ x,         // [512][1024] int32
    const float* __restrict__ w_hh,    // [512][128] f32
    const void* __restrict__ proj_raw, // [V][512] f32 or bf16 (bias folded)
    const float* __restrict__ w_lin,   // [28][128] f32
    const float* __restrict__ b_lin,   // [28] f32
    float* __restrict__ out)           // [512][28] f32
{
  __shared__ int   tok_lds[2][TSTEPS + TPAD]; // both rows' tokens, padded
  __shared__ short h_lds[2][2][HSTRIDE];      // [buf][row][hcol] bf16, padded

  int tid  = threadIdx.x;
  int wave = tid >> 6;          // 0..3
  int lane = tid & 63;
  int n = lane & 15;            // MFMA col (gate within tile) / A row
  int q = lane >> 4;            // quad
  int sH = q >> 1;              // this lane's owned s-slice
  int grow = q & 1;             // this lane's batch row
  int r0 = blockIdx.x * 2;      // first batch row

  int ghcol = wave * 32 + sH * 16 + n;   // this lane's hidden column

  // --- preload tokens (2 rows) -----------------------------------------
  for (int i = tid; i < TSTEPS; i += 256){
    tok_lds[0][i] = x[(long)r0 * TSTEPS + i];
    tok_lds[1][i] = x[(long)(r0 + 1) * TSTEPS + i];
  }

  // --- preload B-frags: w_hh (f32 -> bf16), 8 tiles per wave ------------
  // tile (t,s): gate base n0 = t*128 + wave*32 + s*16
  // B[k=ch*32+q*8+j][n] = w_hh[n0+n][k]
  short8 Bw[4][2][4];
  #pragma unroll
  for (int t = 0; t < 4; ++t)
    #pragma unroll
    for (int s = 0; s < 2; ++s){
      int n0 = t * 128 + wave * 32 + s * 16;
      const float* wr = w_hh + (long)(n0 + n) * HID;
      #pragma unroll
      for (int ch = 0; ch < 4; ++ch)
        #pragma unroll
        for (int j = 0; j < 8; ++j)
          Bw[t][s][ch][j] = (short)f2bf(wr[ch * 32 + q * 8 + j]);
    }

  // zero h buffers incl. pads (h0 = 0)
  for (int i = tid; i < 2 * 2 * HSTRIDE; i += 256) ((short*)h_lds)[i] = 0;

  float c_state = 0.f;                   // every lane owns one cell
  int   arow  = (n >> 2) & 1;            // h row this lane supplies to A

  f32x4 acc[4][2] = {};                  // reg0 re-inited per step

  const float*          prf = (const float*)proj_raw;
  const unsigned short* prb = (const unsigned short*)proj_raw;

  __syncthreads();                       // tokens + h zeros

  // --- depth-2 gx prefetch: own cell only, constant-indexed -------------
  float          gxA[4], gxB[4];
  unsigned short hxA[4], hxB[4];
  {
    long b0 = (long)tok_lds[grow][0] * GATES + ghcol;
    long b1 = (long)tok_lds[grow][1] * GATES + ghcol;
    if constexpr (GXF32){
      #pragma unroll
      for (int t = 0; t < 4; ++t){ gxA[t] = prf[b0 + t * 128]; gxB[t] = prf[b1 + t * 128]; }
    } else {
      #pragma unroll
      for (int t = 0; t < 4; ++t){ hxA[t] = prb[b0 + t * 128]; hxB[t] = prb[b1 + t * 128]; }
    }
  }

#define SUBSTEP(RB, GX, HX, NSTEP)                                            \
  {                                                                           \
    short8 Af[4];                                                             \
    _Pragma("unroll")                                                         \
    for (int ch = 0; ch < 4; ++ch)                                            \
      Af[ch] = *(const short8*)(&h_lds[RB][arow][ch * 32 + q * 8]);           \
    _Pragma("unroll")                                                         \
    for (int t = 0; t < 4; ++t){                                              \
      float gv;                                                               \
      if constexpr (GXF32) gv = GX[t]; else gv = bf2f(HX[t]);                 \
      acc[t][0][0] = (sH == 0) ? gv : 0.f;                                    \
      acc[t][1][0] = (sH == 1) ? gv : 0.f;                                    \
    }                                                                         \
    {                                                                         \
      int ns = (NSTEP) < TSTEPS ? (NSTEP) : TSTEPS - 1;                       \
      long base = (long)tok_lds[grow][ns] * GATES + ghcol;                    \
      if constexpr (GXF32){                                                   \
        _Pragma("unroll")                                                     \
        for (int t = 0; t < 4; ++t) GX[t] = prf[base + t * 128];              \
      } else {                                                                \
        _Pragma("unroll")                                                     \
        for (int t = 0; t < 4; ++t) HX[t] = prb[base + t * 128];              \
      }                                                                       \
    }                                                                         \
    _Pragma("unroll")                                                         \
    for (int ch = 0; ch < 4; ++ch)                                            \
      _Pragma("unroll")                                                       \
      for (int t = 0; t < 4; ++t)                                             \
        _Pragma("unroll")                                                     \
        for (int s = 0; s < 2; ++s)                                           \
          acc[t][s] = __builtin_amdgcn_mfma_f32_16x16x32_bf16(                \
              Af[ch], Bw[t][s][ch], acc[t][s], 0, 0, 0);                      \
    {                                                                         \
      float gi = sH ? acc[0][1][0] : acc[0][0][0];                            \
      float gf = sH ? acc[1][1][0] : acc[1][0][0];                            \
      float gg = sH ? acc[2][1][0] : acc[2][0][0];                            \
      float go = sH ? acc[3][1][0] : acc[3][0][0];                            \
      float si = sigf(gi), sf = sigf(gf), so = sigf(go);                      \
      float tg = tanhf_fast(gg);                                              \
      c_state = sf * c_state + si * tg;                                       \
      float hv = so * tanhf_fast(c_state);                                    \
      h_lds[(RB) ^ 1][grow][ghcol] = (short)f2bf(hv);                         \
    }                                                                         \
    BAR_LGKM();                                                               \
  }

  for (int step = 0; step < TSTEPS; step += 2){
    SUBSTEP(0, gxA, hxA, step + 2)
    SUBSTEP(1, gxB, hxB, step + 3)
  }
#undef SUBSTEP

  // --- final linear: out[r0+b][j] = h[b] . w_lin[j] + b_lin[j] ----------
  // TSTEPS even -> final h is in h_lds[0]
  if (tid < 2 * NCLS){
    int b = tid / NCLS, j = tid - b * NCLS;
    float acc2 = b_lin[j];
    const float* wl = w_lin + (long)j * HID;
    #pragma unroll 4
    for (int k = 0; k < HID; ++k)
      acc2 += bf2f((unsigned short)h_lds[0][b][k]) * wl[k];
    out[(long)(r0 + b) * NCLS + j] = acc2;
  }
}

// ---------------------------------------------------------------------------
extern "C" void kernel_launch(void* const* d_in, const int* in_sizes, int n_in,
                              void* d_out, int out_size, void* d_ws, size_t ws_size,
                              hipStream_t stream)
{
  const int*   x     = (const int*)d_in[0];
  const float* emb   = (const float*)d_in[1];
  const float* w_ih  = (const float*)d_in[2];
  const float* w_hh  = (const float*)d_in[3];
  const float* b_ih  = (const float*)d_in[4];
  const float* b_hh  = (const float*)d_in[5];
  const float* w_lin = (const float*)d_in[6];
  const float* b_lin = (const float*)d_in[7];
  float*       out   = (float*)d_out;

  size_t need_f32 = (size_t)VOCAB * GATES * sizeof(float);   // ~103 MB
  int vblocks = (VOCAB + 15) / 16;   // 3142

  if (ws_size >= need_f32){
    emb_proj_kernel<true><<<dim3(vblocks), dim3(256), 0, stream>>>(
        emb, w_ih, b_ih, b_hh, d_ws);
    lstm_kernel<true><<<dim3(BATCH / 2), dim3(256), 0, stream>>>(
        x, w_hh, d_ws, w_lin, b_lin, out);
  } else {
    emb_proj_kernel<false><<<dim3(vblocks), dim3(256), 0, stream>>>(
        emb, w_ih, b_ih, b_hh, d_ws);
    lstm_kernel<false><<<dim3(BATCH / 2), dim3(256), 0, stream>>>(
        x, w_hh, d_ws, w_lin, b_lin, out);
  }
}

// Round 10
// 597.222 us; speedup vs baseline: 1.1625x; 1.1625x over previous
//
#include <hip/hip_runtime.h>

#define HID    128
#define GATES  512      // 4*HID
#define EMB    64
#define TSTEPS 1024
#define BATCH  512
#define VOCAB  50257
#define NCLS   28
#define HSTRIDE 160     // h row stride in shorts: 320B = 16 banks mod 32
#define TPAD   8        // token row pad (ints): rows land on different banks
#define TTAIL  4        // token tail pad: prefetch never needs a clamp

// gate pre-scale folded into proj and w_hh: i,f,o -> -log2(e); g -> -2log2(e)
#define S_SIG  (-1.442695041f)
#define S_TANH (-2.885390082f)

typedef __attribute__((ext_vector_type(8))) short short8;   // 8 bf16 = 4 VGPRs
typedef __attribute__((ext_vector_type(4))) float f32x4;
typedef __attribute__((ext_vector_type(4))) unsigned short us4;

// lgkm-only barrier: LDS visibility without draining global (vmcnt) loads.
#define BAR_LGKM() __asm__ __volatile__("s_waitcnt lgkmcnt(0)\n\ts_barrier" ::: "memory")

static __device__ __forceinline__ float bf2f(unsigned short u){
  union { unsigned int i; float f; } v; v.i = ((unsigned int)u) << 16; return v.f;
}
static __device__ __forceinline__ unsigned short f2bf(float f){
  union { float ff; unsigned int i; } v; v.ff = f;
  unsigned int x = v.i;
  x += 0x7fffu + ((x >> 16) & 1u);   // round-to-nearest-even
  return (unsigned short)(x >> 16);
}
// pre-scaled sigmoid: y = -log2(e)*x already applied
static __device__ __forceinline__ float sig_pre(float y){
  return __builtin_amdgcn_rcpf(1.f + __builtin_amdgcn_exp2f(y));
}
// pre-scaled tanh: y = -2log2(e)*x already applied; clamp vs exp2 overflow
static __device__ __forceinline__ float tanh_pre(float y){
  float e = __builtin_amdgcn_exp2f(fminf(y, 126.f));
  return (1.f - e) * __builtin_amdgcn_rcpf(1.f + e);
}

// ---------------------------------------------------------------------------
// Phase 1: proj2[v][hcol][type] = s_type * (emb[v]·w_ih[g] + b_ih[g] + b_hh[g]),
// g = type*128 + hcol. f32 inputs; split-bf16 (hi+lo) MFMA -> f32-accurate.
// Interleaved [hcol][type] layout (lstm gathers one dwordx4 per lane),
// staged through LDS so global stores stay coalesced.
// ---------------------------------------------------------------------------
template<bool STORE_F32>
__global__ __launch_bounds__(256) void emb_proj_kernel(
    const float* __restrict__ emb,     // [V][64]
    const float* __restrict__ w_ih,    // [512][64]
    const float* __restrict__ b_ih,    // [512]
    const float* __restrict__ b_hh,    // [512]
    void* __restrict__ proj_raw)       // [V][512] interleaved f32 or bf16
{
  __shared__ float stage[16][516];     // [vrow][hcol*4+type], padded row

  int wave = threadIdx.x >> 6;         // 0..3 == gate type t
  int lane = threadIdx.x & 63;
  int n = lane & 15;
  int q = lane >> 4;
  long v0 = (long)blockIdx.x * 16;
  const float scl = (wave == 2) ? S_TANH : S_SIG;

  long vrow = v0 + n; if (vrow >= VOCAB) vrow = VOCAB - 1;
  const float* er = emb + vrow * EMB;
  short8 ahi[2], alo[2];
  #pragma unroll
  for (int ch = 0; ch < 2; ++ch){
    #pragma unroll
    for (int j = 0; j < 8; ++j){
      float xv = er[ch * 32 + q * 8 + j];
      unsigned short h = f2bf(xv);
      float r = xv - bf2f(h);
      ahi[ch][j] = (short)h;
      alo[ch][j] = (short)f2bf(r);
    }
  }

  #pragma unroll
  for (int i = 0; i < 8; ++i){
    int g0 = (wave * 8 + i) * 16;               // gate base; type = wave
    const float* wr = w_ih + (long)(g0 + n) * EMB;
    short8 bhi[2], blo[2];
    #pragma unroll
    for (int ch = 0; ch < 2; ++ch){
      #pragma unroll
      for (int j = 0; j < 8; ++j){
        float xv = wr[ch * 32 + q * 8 + j];
        unsigned short h = f2bf(xv);
        float r = xv - bf2f(h);
        bhi[ch][j] = (short)h;
        blo[ch][j] = (short)f2bf(r);
      }
    }
    float bias = b_ih[g0 + n] + b_hh[g0 + n];
    f32x4 acc = {bias, bias, bias, bias};
    #pragma unroll
    for (int ch = 0; ch < 2; ++ch){
      acc = __builtin_amdgcn_mfma_f32_16x16x32_bf16(ahi[ch], bhi[ch], acc, 0, 0, 0);
      acc = __builtin_amdgcn_mfma_f32_16x16x32_bf16(ahi[ch], blo[ch], acc, 0, 0, 0);
      acc = __builtin_amdgcn_mfma_f32_16x16x32_bf16(alo[ch], bhi[ch], acc, 0, 0, 0);
    }
    // C/D: row = 4q+r (vocab row), col = n; hcol = i*16+n, type = wave
    #pragma unroll
    for (int r = 0; r < 4; ++r)
      stage[q * 4 + r][(i * 16 + n) * 4 + wave] = scl * acc[r];
  }
  __syncthreads();

  // coalesced store: lane handles 32 consecutive values of one vocab row
  {
    int row = threadIdx.x >> 4;          // 0..15
    int c0  = (threadIdx.x & 15) * 32;   // 0..480
    long grow = v0 + row;
    if (grow < VOCAB){
      if (STORE_F32){
        float* dst = (float*)proj_raw + grow * GATES + c0;
        #pragma unroll
        for (int k = 0; k < 8; ++k)
          *(f32x4*)(dst + k * 4) = *(const f32x4*)(&stage[row][c0 + k * 4]);
      } else {
        unsigned short* dst = (unsigned short*)proj_raw + grow * GATES + c0;
        #pragma unroll
        for (int k = 0; k < 32; ++k)
          dst[k] = f2bf(stage[row][c0 + k]);
      }
    }
  }
}

// ---------------------------------------------------------------------------
// Phase 2: LSTM recurrence + final linear. R7 structure (best known):
// 256 blocks x 512 threads (8 waves), R=2 rows/block, 2 waves/SIMD.
// A = h rows (batch0 -> A rows 0-3/8-11, batch1 -> 4-7/12-15), B = w_hh
// static in regs (pre-scaled by gate type). q<2 lanes own cell (row q,
// hcol wave*16+n) in acc[t] reg0 -> in-register nonlinearity (pre-scaled
// trans, no per-cell scaling muls). Gather: ONE dwordx4 per lane from the
// interleaved proj. Token rows bank-padded. One lgkm-only barrier/step.
// ---------------------------------------------------------------------------
template<bool GXF32>
__global__ __launch_bounds__(512, 2) void lstm_kernel(
    const int* __restrict__ x,         // [512][1024] int32
    const float* __restrict__ w_hh,    // [512][128] f32
    const void* __restrict__ proj_raw, // [V][512] interleaved (bias+scale folded)
    const float* __restrict__ w_lin,   // [28][128] f32
    const float* __restrict__ b_lin,   // [28] f32
    float* __restrict__ out)           // [512][28] f32
{
  __shared__ int   tok_lds[2][TSTEPS + TPAD];  // bank-padded rows + tail
  __shared__ short h_lds[2][2][HSTRIDE];       // [buf][row][hcol] bf16, padded

  int tid  = threadIdx.x;
  int wave = tid >> 6;          // 0..7
  int lane = tid & 63;
  int n = lane & 15;            // MFMA col (gate within tile) / A row
  int q = lane >> 4;            // quad
  int r0 = blockIdx.x * 2;      // first batch row

  // --- preload tokens (2 rows, tail-padded with last token) -------------
  for (int i = tid; i < TSTEPS + TTAIL; i += 512){
    int src = i < TSTEPS ? i : TSTEPS - 1;
    tok_lds[0][i] = x[(long)r0 * TSTEPS + src];
    tok_lds[1][i] = x[(long)(r0 + 1) * TSTEPS + src];
  }

  // --- preload B-frags: w_hh (f32 -> bf16, pre-scaled), 4 tiles/wave ----
  // tile t: gate base n0 = t*128 + wave*16; B[k=ch*32+q*8+j][n] = s_t*w_hh[n0+n][k]
  short8 Bw[4][4];
  #pragma unroll
  for (int t = 0; t < 4; ++t){
    int n0 = t * 128 + wave * 16;
    const float scl = (t == 2) ? S_TANH : S_SIG;
    const float* wr = w_hh + (long)(n0 + n) * HID;
    #pragma unroll
    for (int ch = 0; ch < 4; ++ch)
      #pragma unroll
      for (int j = 0; j < 8; ++j)
        Bw[t][ch][j] = (short)f2bf(scl * wr[ch * 32 + q * 8 + j]);
  }

  // zero h buffers incl. pads (h0 = 0)
  for (int i = tid; i < 2 * 2 * HSTRIDE; i += 512) ((short*)h_lds)[i] = 0;

  float c_state = 0.f;                   // q<2 lanes: cell (row q, hcol)
  bool  nlact = (q < 2);
  int   arow  = (n >> 2) & 1;            // h row this lane supplies to A
  int   grow  = q & 1;                   // gx row this lane gathers

  f32x4 acc[4] = {};                     // reg0 re-inited per step

  const float*          prf = (const float*)proj_raw;
  const unsigned short* prb = (const unsigned short*)proj_raw;
  int ghcol = wave * 16 + n;             // this lane's hidden column

  __syncthreads();                       // tokens + h zeros

  // --- depth-2 gx prefetch: one vector reg per buffer -------------------
  f32x4 gxA, gxB;
  us4   hxA, hxB;
  {
    if constexpr (GXF32){
      gxA = *(const f32x4*)(prf + (long)tok_lds[grow][0] * GATES + ghcol * 4);
      gxB = *(const f32x4*)(prf + (long)tok_lds[grow][1] * GATES + ghcol * 4);
    } else {
      hxA = *(const us4*)(prb + (long)tok_lds[grow][0] * GATES + ghcol * 4);
      hxB = *(const us4*)(prb + (long)tok_lds[grow][1] * GATES + ghcol * 4);
    }
  }

#define SUBSTEP(RB, GX, HX, NSTEP)                                            \
  {                                                                           \
    short8 Af[4];                                                             \
    _Pragma("unroll")                                                         \
    for (int ch = 0; ch < 4; ++ch)                                            \
      Af[ch] = *(const short8*)(&h_lds[RB][arow][ch * 32 + q * 8]);           \
    _Pragma("unroll")                                                         \
    for (int t = 0; t < 4; ++t){                                              \
      if constexpr (GXF32) acc[t][0] = GX[t];                                 \
      else                 acc[t][0] = bf2f(HX[t]);                           \
    }                                                                         \
    if constexpr (GXF32)                                                      \
      GX = *(const f32x4*)(prf + (long)tok_lds[grow][NSTEP] * GATES + ghcol * 4); \
    else                                                                      \
      HX = *(const us4*)(prb + (long)tok_lds[grow][NSTEP] * GATES + ghcol * 4);   \
    _Pragma("unroll")                                                         \
    for (int ch = 0; ch < 4; ++ch)                                            \
      _Pragma("unroll")                                                       \
      for (int t = 0; t < 4; ++t)                                             \
        acc[t] = __builtin_amdgcn_mfma_f32_16x16x32_bf16(                     \
            Af[ch], Bw[t][ch], acc[t], 0, 0, 0);                              \
    if (nlact){                                                               \
      float si = sig_pre(acc[0][0]), sf = sig_pre(acc[1][0]);                 \
      float so = sig_pre(acc[3][0]);                                          \
      float tg = tanh_pre(acc[2][0]);                                         \
      c_state = sf * c_state + si * tg;                                       \
      float hv = so * tanh_pre(S_TANH * c_state);                             \
      h_lds[(RB) ^ 1][q][ghcol] = (short)f2bf(hv);                            \
    }                                                                         \
    BAR_LGKM();                                                               \
  }

  for (int step = 0; step < TSTEPS; step += 2){
    SUBSTEP(0, gxA, hxA, step + 2)
    SUBSTEP(1, gxB, hxB, step + 3)
  }
#undef SUBSTEP

  // --- final linear: out[r0+b][j] = h[b] . w_lin[j] + b_lin[j] ----------
  // TSTEPS even -> final h is in h_lds[0]
  if (tid < 2 * NCLS){
    int b = tid / NCLS, j = tid - b * NCLS;
    float acc2 = b_lin[j];
    const float* wl = w_lin + (long)j * HID;
    #pragma unroll 4
    for (int k = 0; k < HID; ++k)
      acc2 += bf2f((unsigned short)h_lds[0][b][k]) * wl[k];
    out[(long)(r0 + b) * NCLS + j] = acc2;
  }
}

// ---------------------------------------------------------------------------
extern "C" void kernel_launch(void* const* d_in, const int* in_sizes, int n_in,
                              void* d_out, int out_size, void* d_ws, size_t ws_size,
                              hipStream_t stream)
{
  const int*   x     = (const int*)d_in[0];
  const float* emb   = (const float*)d_in[1];
  const float* w_ih  = (const float*)d_in[2];
  const float* w_hh  = (const float*)d_in[3];
  const float* b_ih  = (const float*)d_in[4];
  const float* b_hh  = (const float*)d_in[5];
  const float* w_lin = (const float*)d_in[6];
  const float* b_lin = (const float*)d_in[7];
  float*       out   = (float*)d_out;

  size_t need_f32 = (size_t)VOCAB * GATES * sizeof(float);   // ~103 MB
  int vblocks = (VOCAB + 15) / 16;   // 3142

  if (ws_size >= need_f32){
    emb_proj_kernel<true><<<dim3(vblocks), dim3(256), 0, stream>>>(
        emb, w_ih, b_ih, b_hh, d_ws);
    lstm_kernel<true><<<dim3(BATCH / 2), dim3(512), 0, stream>>>(
        x, w_hh, d_ws, w_lin, b_lin, out);
  } else {
    emb_proj_kernel<false><<<dim3(vblocks), dim3(256), 0, stream>>>(
        emb, w_ih, b_ih, b_hh, d_ws);
    lstm_kernel<false><<<dim3(BATCH / 2), dim3(512), 0, stream>>>(
        x, w_hh, d_ws, w_lin, b_lin, out);
  }
}

// Round 11
// 589.540 us; speedup vs baseline: 1.1777x; 1.0130x over previous
//
#include <hip/hip_runtime.h>

#define HID    128
#define GATES  512      // 4*HID
#define EMB    64
#define TSTEPS 1024
#define BATCH  512
#define VOCAB  50257
#define NCLS   28
#define HSTRIDE 160     // h row stride in shorts: 320B = 16 banks mod 32
#define TPAD   8        // token row pad (ints): rows land on different banks
#define TTAIL  4        // token tail pad: prefetch never needs a clamp

// gate pre-scale folded into proj and w_hh: i,f,o -> -log2(e); g -> -2log2(e)
#define S_SIG  (-1.442695041f)
#define S_TANH (-2.885390082f)

typedef __attribute__((ext_vector_type(8))) short short8;   // 8 bf16 = 4 VGPRs
typedef __attribute__((ext_vector_type(4))) float f32x4;
typedef __attribute__((ext_vector_type(4))) unsigned short us4;

// lgkm-only barrier: LDS visibility without draining global (vmcnt) loads.
#define BAR_LGKM() __asm__ __volatile__("s_waitcnt lgkmcnt(0)\n\ts_barrier" ::: "memory")

static __device__ __forceinline__ float bf2f(unsigned short u){
  union { unsigned int i; float f; } v; v.i = ((unsigned int)u) << 16; return v.f;
}
static __device__ __forceinline__ unsigned short f2bf(float f){
  union { float ff; unsigned int i; } v; v.ff = f;
  unsigned int x = v.i;
  x += 0x7fffu + ((x >> 16) & 1u);   // round-to-nearest-even
  return (unsigned short)(x >> 16);
}
// pre-scaled sigmoid: y = -log2(e)*x already applied.
// No clamp needed: exp2(+inf)->inf -> rcp(inf)=0; exp2(-big)->0 -> 1. Both correct.
static __device__ __forceinline__ float sig_pre(float y){
  return __builtin_amdgcn_rcpf(1.f + __builtin_amdgcn_exp2f(y));
}
// pre-scaled tanh: y = -2log2(e)*x already applied; clamp vs (1-inf)*0 = NaN
static __device__ __forceinline__ float tanh_pre(float y){
  float e = __builtin_amdgcn_exp2f(fminf(y, 126.f));
  return (1.f - e) * __builtin_amdgcn_rcpf(1.f + e);
}

// ---------------------------------------------------------------------------
// Phase 1: proj[v][hcol][type] = s_type * (emb[v]·w_ih[g] + b_ih[g] + b_hh[g]),
// g = type*128 + hcol, stored bf16 (halves write traffic + gather traffic).
// f32 inputs; split-bf16 (hi+lo) MFMA -> f32-accurate pre-activation, rounded
// once to bf16. Staged through LDS so global stores stay coalesced.
// ---------------------------------------------------------------------------
__global__ __launch_bounds__(256) void emb_proj_kernel(
    const float* __restrict__ emb,     // [V][64]
    const float* __restrict__ w_ih,    // [512][64]
    const float* __restrict__ b_ih,    // [512]
    const float* __restrict__ b_hh,    // [512]
    unsigned short* __restrict__ proj) // [V][512] interleaved bf16
{
  __shared__ float stage[16][516];     // [vrow][hcol*4+type], padded row

  int wave = threadIdx.x >> 6;         // 0..3 == gate type t
  int lane = threadIdx.x & 63;
  int n = lane & 15;
  int q = lane >> 4;
  long v0 = (long)blockIdx.x * 16;
  const float scl = (wave == 2) ? S_TANH : S_SIG;

  long vrow = v0 + n; if (vrow >= VOCAB) vrow = VOCAB - 1;
  const float* er = emb + vrow * EMB;
  short8 ahi[2], alo[2];
  #pragma unroll
  for (int ch = 0; ch < 2; ++ch){
    #pragma unroll
    for (int j = 0; j < 8; ++j){
      float xv = er[ch * 32 + q * 8 + j];
      unsigned short h = f2bf(xv);
      float r = xv - bf2f(h);
      ahi[ch][j] = (short)h;
      alo[ch][j] = (short)f2bf(r);
    }
  }

  #pragma unroll
  for (int i = 0; i < 8; ++i){
    int g0 = (wave * 8 + i) * 16;               // gate base; type = wave
    const float* wr = w_ih + (long)(g0 + n) * EMB;
    short8 bhi[2], blo[2];
    #pragma unroll
    for (int ch = 0; ch < 2; ++ch){
      #pragma unroll
      for (int j = 0; j < 8; ++j){
        float xv = wr[ch * 32 + q * 8 + j];
        unsigned short h = f2bf(xv);
        float r = xv - bf2f(h);
        bhi[ch][j] = (short)h;
        blo[ch][j] = (short)f2bf(r);
      }
    }
    float bias = b_ih[g0 + n] + b_hh[g0 + n];
    f32x4 acc = {bias, bias, bias, bias};
    #pragma unroll
    for (int ch = 0; ch < 2; ++ch){
      acc = __builtin_amdgcn_mfma_f32_16x16x32_bf16(ahi[ch], bhi[ch], acc, 0, 0, 0);
      acc = __builtin_amdgcn_mfma_f32_16x16x32_bf16(ahi[ch], blo[ch], acc, 0, 0, 0);
      acc = __builtin_amdgcn_mfma_f32_16x16x32_bf16(alo[ch], bhi[ch], acc, 0, 0, 0);
    }
    // C/D: row = 4q+r (vocab row), col = n; hcol = i*16+n, type = wave
    #pragma unroll
    for (int r = 0; r < 4; ++r)
      stage[q * 4 + r][(i * 16 + n) * 4 + wave] = scl * acc[r];
  }
  __syncthreads();

  // coalesced store: lane handles 32 consecutive bf16 of one vocab row (64 B)
  {
    int row = threadIdx.x >> 4;          // 0..15
    int c0  = (threadIdx.x & 15) * 32;   // 0..480
    long grow = v0 + row;
    if (grow < VOCAB){
      unsigned short* dst = proj + grow * GATES + c0;
      #pragma unroll
      for (int k = 0; k < 8; ++k){
        us4 v;
        #pragma unroll
        for (int m = 0; m < 4; ++m) v[m] = f2bf(stage[row][c0 + k * 4 + m]);
        *(us4*)(dst + k * 4) = v;
      }
    }
  }
}

// ---------------------------------------------------------------------------
// Phase 2: LSTM recurrence + final linear. R10 structure + 3 trims:
// (1) s_setprio stagger: waves 0-3 prio 1 -> their MFMAs drain first, their
//     nonlin VALU overlaps waves 4-7's MFMA drain (de-phase the two waves
//     sharing each SIMD instead of serializing MFMA then VALU).
// (2) tokens stored PRE-MULTIPLIED by GATES -> gather addr = base + off
//     (no per-substep 64-bit mad on the chain).
// (3) proj is bf16 -> dwordx2 gather, half FETCH traffic.
// ---------------------------------------------------------------------------
__global__ __launch_bounds__(512, 2) void lstm_kernel(
    const int* __restrict__ x,           // [512][1024] int32
    const float* __restrict__ w_hh,      // [512][128] f32
    const unsigned short* __restrict__ proj, // [V][512] bf16 interleaved
    const float* __restrict__ w_lin,     // [28][128] f32
    const float* __restrict__ b_lin,     // [28] f32
    float* __restrict__ out)             // [512][28] f32
{
  __shared__ int   tok_lds[2][TSTEPS + TPAD];  // tok*GATES, bank-padded rows
  __shared__ short h_lds[2][2][HSTRIDE];       // [buf][row][hcol] bf16, padded

  int tid  = threadIdx.x;
  int wave = tid >> 6;          // 0..7
  int lane = tid & 63;
  int n = lane & 15;            // MFMA col (gate within tile) / A row
  int q = lane >> 4;            // quad
  int r0 = blockIdx.x * 2;      // first batch row

  // --- preload tokens (pre-multiplied element offsets) ------------------
  for (int i = tid; i < TSTEPS + TTAIL; i += 512){
    int src = i < TSTEPS ? i : TSTEPS - 1;
    tok_lds[0][i] = x[(long)r0 * TSTEPS + src] * GATES;
    tok_lds[1][i] = x[(long)(r0 + 1) * TSTEPS + src] * GATES;
  }

  // --- preload B-frags: w_hh (f32 -> bf16, pre-scaled), 4 tiles/wave ----
  short8 Bw[4][4];
  #pragma unroll
  for (int t = 0; t < 4; ++t){
    int n0 = t * 128 + wave * 16;
    const float scl = (t == 2) ? S_TANH : S_SIG;
    const float* wr = w_hh + (long)(n0 + n) * HID;
    #pragma unroll
    for (int ch = 0; ch < 4; ++ch)
      #pragma unroll
      for (int j = 0; j < 8; ++j)
        Bw[t][ch][j] = (short)f2bf(scl * wr[ch * 32 + q * 8 + j]);
  }

  // zero h buffers incl. pads (h0 = 0)
  for (int i = tid; i < 2 * 2 * HSTRIDE; i += 512) ((short*)h_lds)[i] = 0;

  float c_state = 0.f;                   // q<2 lanes: cell (row q, hcol)
  bool  nlact = (q < 2);
  int   arow  = (n >> 2) & 1;            // h row this lane supplies to A
  int   grow  = q & 1;                   // gx row this lane gathers

  f32x4 acc[4] = {};                     // reg0 re-inited per step
  int ghcol4 = (wave * 16 + n) * 4;      // element offset within a proj row

  __syncthreads();                       // tokens + h zeros

  // wave stagger: waves 0-3 issue-priority 1 (their MFMAs drain first,
  // their nonlin overlaps waves 4-7's MFMA drain on the shared SIMD)
  if (wave < 4) __asm__ __volatile__("s_setprio 1");

  // --- depth-2 gx prefetch ----------------------------------------------
  us4 hxA, hxB;
  hxA = *(const us4*)(proj + (long)(tok_lds[grow][0] + ghcol4));
  hxB = *(const us4*)(proj + (long)(tok_lds[grow][1] + ghcol4));

#define SUBSTEP(RB, HX, NSTEP)                                                \
  {                                                                           \
    short8 Af[4];                                                             \
    _Pragma("unroll")                                                         \
    for (int ch = 0; ch < 4; ++ch)                                            \
      Af[ch] = *(const short8*)(&h_lds[RB][arow][ch * 32 + q * 8]);           \
    _Pragma("unroll")                                                         \
    for (int t = 0; t < 4; ++t) acc[t][0] = bf2f(HX[t]);                      \
    HX = *(const us4*)(proj + (long)(tok_lds[grow][NSTEP] + ghcol4));         \
    _Pragma("unroll")                                                         \
    for (int ch = 0; ch < 4; ++ch)                                            \
      _Pragma("unroll")                                                       \
      for (int t = 0; t < 4; ++t)                                             \
        acc[t] = __builtin_amdgcn_mfma_f32_16x16x32_bf16(                     \
            Af[ch], Bw[t][ch], acc[t], 0, 0, 0);                              \
    if (nlact){                                                               \
      float si = sig_pre(acc[0][0]), sf = sig_pre(acc[1][0]);                 \
      float so = sig_pre(acc[3][0]);                                          \
      float tg = tanh_pre(acc[2][0]);                                         \
      c_state = sf * c_state + si * tg;                                       \
      float hv = so * tanh_pre(S_TANH * c_state);                             \
      h_lds[(RB) ^ 1][q][wave * 16 + n] = (short)f2bf(hv);                    \
    }                                                                         \
    BAR_LGKM();                                                               \
  }

  for (int step = 0; step < TSTEPS; step += 2){
    SUBSTEP(0, hxA, step + 2)
    SUBSTEP(1, hxB, step + 3)
  }
#undef SUBSTEP

  // --- final linear: out[r0+b][j] = h[b] . w_lin[j] + b_lin[j] ----------
  // TSTEPS even -> final h is in h_lds[0]
  if (tid < 2 * NCLS){
    int b = tid / NCLS, j = tid - b * NCLS;
    float acc2 = b_lin[j];
    const float* wl = w_lin + (long)j * HID;
    #pragma unroll 4
    for (int k = 0; k < HID; ++k)
      acc2 += bf2f((unsigned short)h_lds[0][b][k]) * wl[k];
    out[(long)(r0 + b) * NCLS + j] = acc2;
  }
}

// ---------------------------------------------------------------------------
extern "C" void kernel_launch(void* const* d_in, const int* in_sizes, int n_in,
                              void* d_out, int out_size, void* d_ws, size_t ws_size,
                              hipStream_t stream)
{
  const int*   x     = (const int*)d_in[0];
  const float* emb   = (const float*)d_in[1];
  const float* w_ih  = (const float*)d_in[2];
  const float* w_hh  = (const float*)d_in[3];
  const float* b_ih  = (const float*)d_in[4];
  const float* b_hh  = (const float*)d_in[5];
  const float* w_lin = (const float*)d_in[6];
  const float* b_lin = (const float*)d_in[7];
  float*       out   = (float*)d_out;
  unsigned short* proj = (unsigned short*)d_ws;   // [V][512] bf16, ~51.5 MB

  int vblocks = (VOCAB + 15) / 16;   // 3142
  emb_proj_kernel<<<dim3(vblocks), dim3(256), 0, stream>>>(
      emb, w_ih, b_ih, b_hh, proj);
  lstm_kernel<<<dim3(BATCH / 2), dim3(512), 0, stream>>>(
      x, w_hh, proj, w_lin, b_lin, out);
}

// Round 12
// 531.601 us; speedup vs baseline: 1.3060x; 1.1090x over previous
//
#include <hip/hip_runtime.h>

#define HID    128
#define GATES  512      // 4*HID
#define EMB    64
#define TSTEPS 1024
#define BATCH  512
#define VOCAB  50257
#define NCLS   28
#define H8STRIDE 160    // h row stride in BYTES (i8 h): 40 dwords = 8 banks mod 32
#define TPAD   8        // token row pad (ints): rows land on different banks
#define TTAIL  4        // token tail pad: prefetch never needs a clamp

// gate pre-scale folded into proj and w_hh scales: i,f,o -> -log2e; g -> -2log2e
#define S_SIG  (-1.442695041f)
#define S_TANH (-2.885390082f)

typedef __attribute__((ext_vector_type(8))) short short8;   // 8 bf16 = 4 VGPRs
typedef __attribute__((ext_vector_type(4))) float f32x4;
typedef __attribute__((ext_vector_type(4))) unsigned short us4;
typedef __attribute__((ext_vector_type(4))) int int4v;

// lgkm-only barrier: LDS visibility without draining global (vmcnt) loads.
#define BAR_LGKM() __asm__ __volatile__("s_waitcnt lgkmcnt(0)\n\ts_barrier" ::: "memory")

static __device__ __forceinline__ float bf2f(unsigned short u){
  union { unsigned int i; float f; } v; v.i = ((unsigned int)u) << 16; return v.f;
}
static __device__ __forceinline__ unsigned short f2bf(float f){
  union { float ff; unsigned int i; } v; v.ff = f;
  unsigned int x = v.i;
  x += 0x7fffu + ((x >> 16) & 1u);   // round-to-nearest-even
  return (unsigned short)(x >> 16);
}

// ---------------------------------------------------------------------------
// Phase 0: split w_ih into bf16 hi/lo once (emb_proj blocks re-used to redo
// this per block -> ~1500 VALU inst/block; now they just vector-load it).
// ---------------------------------------------------------------------------
__global__ __launch_bounds__(256) void wsplit_kernel(
    const float* __restrict__ w_ih,    // [512][64]
    unsigned short* __restrict__ whi,  // [512][64] bf16 hi
    unsigned short* __restrict__ wlo)  // [512][64] bf16 lo
{
  int i = blockIdx.x * 256 + threadIdx.x;
  if (i < GATES * EMB){
    float v = w_ih[i];
    unsigned short h = f2bf(v);
    whi[i] = h;
    wlo[i] = f2bf(v - bf2f(h));
  }
}

// ---------------------------------------------------------------------------
// Phase 1: proj[v][hcol][type] = s_type * (emb[v]·w_ih[g] + b_ih[g] + b_hh[g]),
// g = type*128 + hcol, stored bf16 interleaved. Split-bf16 MFMA, f32-accurate.
// ---------------------------------------------------------------------------
__global__ __launch_bounds__(256) void emb_proj_kernel(
    const float* __restrict__ emb,     // [V][64]
    const unsigned short* __restrict__ whi, // [512][64] bf16 hi
    const unsigned short* __restrict__ wlo, // [512][64] bf16 lo
    const float* __restrict__ b_ih,    // [512]
    const float* __restrict__ b_hh,    // [512]
    unsigned short* __restrict__ proj) // [V][512] interleaved bf16
{
  __shared__ float stage[16][516];     // [vrow][hcol*4+type], padded row

  int wave = threadIdx.x >> 6;         // 0..3 == gate type t
  int lane = threadIdx.x & 63;
  int n = lane & 15;
  int q = lane >> 4;
  long v0 = (long)blockIdx.x * 16;
  const float scl = (wave == 2) ? S_TANH : S_SIG;

  long vrow = v0 + n; if (vrow >= VOCAB) vrow = VOCAB - 1;
  const float* er = emb + vrow * EMB;
  short8 ahi[2], alo[2];
  #pragma unroll
  for (int ch = 0; ch < 2; ++ch){
    #pragma unroll
    for (int j = 0; j < 8; ++j){
      float xv = er[ch * 32 + q * 8 + j];
      unsigned short h = f2bf(xv);
      ahi[ch][j] = (short)h;
      alo[ch][j] = (short)f2bf(xv - bf2f(h));
    }
  }

  #pragma unroll
  for (int i = 0; i < 8; ++i){
    int g0 = (wave * 8 + i) * 16;               // gate base; type = wave
    const short* wh = (const short*)whi + (long)(g0 + n) * EMB;
    const short* wl = (const short*)wlo + (long)(g0 + n) * EMB;
    float bias = b_ih[g0 + n] + b_hh[g0 + n];
    f32x4 acc = {bias, bias, bias, bias};
    #pragma unroll
    for (int ch = 0; ch < 2; ++ch){
      short8 bhi = *(const short8*)(wh + ch * 32 + q * 8);
      short8 blo = *(const short8*)(wl + ch * 32 + q * 8);
      acc = __builtin_amdgcn_mfma_f32_16x16x32_bf16(ahi[ch], bhi, acc, 0, 0, 0);
      acc = __builtin_amdgcn_mfma_f32_16x16x32_bf16(ahi[ch], blo, acc, 0, 0, 0);
      acc = __builtin_amdgcn_mfma_f32_16x16x32_bf16(alo[ch], bhi, acc, 0, 0, 0);
    }
    #pragma unroll
    for (int r = 0; r < 4; ++r)
      stage[q * 4 + r][(i * 16 + n) * 4 + wave] = scl * acc[r];
  }
  __syncthreads();

  {
    int row = threadIdx.x >> 4;          // 0..15
    int c0  = (threadIdx.x & 15) * 32;   // 0..480
    long grow = v0 + row;
    if (grow < VOCAB){
      unsigned short* dst = proj + grow * GATES + c0;
      #pragma unroll
      for (int k = 0; k < 8; ++k){
        us4 v;
        #pragma unroll
        for (int m = 0; m < 4; ++m) v[m] = f2bf(stage[row][c0 + k * 4 + m]);
        *(us4*)(dst + k * 4) = v;
      }
    }
  }
}

// ---------------------------------------------------------------------------
// Phase 2: LSTM recurrence + final linear, i8 MFMA edition.
// 256 blocks x 512 threads (8 waves), R=2 rows/block, 2 waves/SIMD.
// gates GEMM via mfma_i32_16x16x64_i8 (K=64): 4 t-tiles x 2 K-chunks =
// 8 MFMA/wave/step (was 16 bf16) -> MFMA pipe floor 620 -> 326 cyc/SIMD.
// h quantized to i8 at scale 127 (h in (-1,1)); w_hh quantized per-gate-row
// at max-scale; dequant gate = i32acc * (s_type*rowmax/127^2) + gx(bf16).
// C/D layout duplicates (rows 8/12) give all 64 lanes a valid gate copy ->
// unconditional nonlinearity; rcp-merged activations (5 exp2 + 3 rcp).
// One lgkm-only barrier/step; depth-2 dwordx2 gx prefetch.
// ---------------------------------------------------------------------------
__global__ __launch_bounds__(512, 2) void lstm_kernel(
    const int* __restrict__ x,           // [512][1024] int32
    const float* __restrict__ w_hh,      // [512][128] f32
    const unsigned short* __restrict__ proj, // [V][512] bf16 interleaved
    const float* __restrict__ w_lin,     // [28][128] f32
    const float* __restrict__ b_lin,     // [28] f32
    float* __restrict__ out)             // [512][28] f32
{
  __shared__ int   tok_lds[2][TSTEPS + TPAD];      // tok*GATES, bank-padded
  __shared__ signed char h8[2][2][H8STRIDE];       // [buf][row][hcol] i8 h

  int tid  = threadIdx.x;
  int wave = tid >> 6;          // 0..7
  int lane = tid & 63;
  int n = lane & 15;            // MFMA col (gate within tile) / A row
  int q = lane >> 4;            // quad
  int r0 = blockIdx.x * 2;      // first batch row

  // --- preload tokens (pre-multiplied element offsets) ------------------
  for (int i = tid; i < TSTEPS + TTAIL; i += 512){
    int src = i < TSTEPS ? i : TSTEPS - 1;
    tok_lds[0][i] = x[(long)r0 * TSTEPS + src] * GATES;
    tok_lds[1][i] = x[(long)(r0 + 1) * TSTEPS + src] * GATES;
  }

  // --- quantize w_hh to i8, per-gate-row max scale ----------------------
  // tile t: gate row = t*128 + wave*16 + n; B[k = ch*64 + q*16 + j][n]
  int4v Bw[4][2];
  float scl[4];
  #pragma unroll
  for (int t = 0; t < 4; ++t){
    int row = t * 128 + wave * 16 + n;
    const float* wr = w_hh + (long)row * HID;
    float vals[2][16];
    float m = 0.f;
    #pragma unroll
    for (int ch = 0; ch < 2; ++ch)
      #pragma unroll
      for (int j = 0; j < 16; ++j){
        float v = wr[ch * 64 + q * 16 + j];
        vals[ch][j] = v;
        m = fmaxf(m, fabsf(v));
      }
    // row is split across the 4 quads (lane ^ 16, lane ^ 32 share the row)
    m = fmaxf(m, __shfl_xor(m, 16, 64));
    m = fmaxf(m, __shfl_xor(m, 32, 64));
    m = fmaxf(m, 1e-20f);
    float qs = 127.f / m;
    #pragma unroll
    for (int ch = 0; ch < 2; ++ch){
      #pragma unroll
      for (int d = 0; d < 4; ++d){
        int b0 = (int)__builtin_rintf(vals[ch][d * 4 + 0] * qs);
        int b1 = (int)__builtin_rintf(vals[ch][d * 4 + 1] * qs);
        int b2 = (int)__builtin_rintf(vals[ch][d * 4 + 2] * qs);
        int b3 = (int)__builtin_rintf(vals[ch][d * 4 + 3] * qs);
        Bw[t][ch][d] = (b0 & 255) | ((b1 & 255) << 8) | ((b2 & 255) << 16) | (b3 << 24);
      }
    }
    scl[t] = ((t == 2) ? S_TANH : S_SIG) * m * (1.f / 16129.f);  // /127^2
  }

  // zero h buffers (h0 = 0)
  for (int i = tid; i < 2 * 2 * H8STRIDE; i += 512) ((signed char*)h8)[i] = 0;

  float c_state = 0.f;                   // q0/q2: row0 cell; q1/q3: row1 (dups)
  bool  nlact = (q < 2);                 // unique owners write h
  int   arow  = (n >> 2) & 1;            // h row this lane supplies to A
  int   grow  = q & 1;                   // gx row this lane gathers
  int   hcol  = wave * 16 + n;

  int4v acc[4] = {};                     // reg0 re-zeroed per step; 1-3 garbage
  int ghcol4 = hcol * 4;                 // element offset within a proj row

  __syncthreads();                       // tokens + h zeros

  // --- depth-2 gx prefetch ----------------------------------------------
  us4 hxA, hxB;
  hxA = *(const us4*)(proj + (long)(tok_lds[grow][0] + ghcol4));
  hxB = *(const us4*)(proj + (long)(tok_lds[grow][1] + ghcol4));

#define SUBSTEP(RB, HX, NSTEP)                                                \
  {                                                                           \
    int4v Af[2];                                                              \
    _Pragma("unroll")                                                         \
    for (int ch = 0; ch < 2; ++ch)                                            \
      Af[ch] = *(const int4v*)(&h8[RB][arow][ch * 64 + q * 16]);              \
    _Pragma("unroll")                                                         \
    for (int t = 0; t < 4; ++t) acc[t][0] = 0;                                \
    us4 hx_cur = HX;                                                          \
    HX = *(const us4*)(proj + (long)(tok_lds[grow][NSTEP] + ghcol4));         \
    _Pragma("unroll")                                                         \
    for (int ch = 0; ch < 2; ++ch)                                            \
      _Pragma("unroll")                                                       \
      for (int t = 0; t < 4; ++t)                                             \
        acc[t] = __builtin_amdgcn_mfma_i32_16x16x64_i8(                       \
            Af[ch], Bw[t][ch], acc[t], 0, 0, 0);                              \
    {                                                                         \
      float g0 = (float)acc[0][0] * scl[0] + bf2f(hx_cur[0]);                 \
      float g1 = (float)acc[1][0] * scl[1] + bf2f(hx_cur[1]);                 \
      float g2 = (float)acc[2][0] * scl[2] + bf2f(hx_cur[2]);                 \
      float g3 = (float)acc[3][0] * scl[3] + bf2f(hx_cur[3]);                 \
      float ei = __builtin_amdgcn_exp2f(g0);                                  \
      float ef = __builtin_amdgcn_exp2f(g1);                                  \
      float eg = __builtin_amdgcn_exp2f(fminf(g2, 126.f));                    \
      float eo = __builtin_amdgcn_exp2f(g3);                                  \
      float r1 = __builtin_amdgcn_rcpf((1.f + ei) * (1.f + eg));              \
      float sitg = (1.f - eg) * r1;           /* si * tg */                   \
      float sf = __builtin_amdgcn_rcpf(1.f + ef);                             \
      c_state = sf * c_state + sitg;                                          \
      float ec = __builtin_amdgcn_exp2f(fminf(S_TANH * c_state, 126.f));      \
      float r2 = __builtin_amdgcn_rcpf((1.f + eo) * (1.f + ec));              \
      float hv = (1.f - ec) * r2;             /* tanh(c) * so */              \
      int qi = (int)__builtin_rintf(hv * 127.f);                              \
      if (nlact) h8[(RB) ^ 1][q][hcol] = (signed char)qi;                     \
    }                                                                         \
    BAR_LGKM();                                                               \
  }

  for (int step = 0; step < TSTEPS; step += 2){
    SUBSTEP(0, hxA, step + 2)
    SUBSTEP(1, hxB, step + 3)
  }
#undef SUBSTEP

  // --- final linear: out[r0+b][j] = (qh[b]/127) . w_lin[j] + b_lin[j] ---
  // TSTEPS even -> final h is in h8[0]
  if (tid < 2 * NCLS){
    int b = tid / NCLS, j = tid - b * NCLS;
    float s = 0.f;
    const float* wl = w_lin + (long)j * HID;
    #pragma unroll 4
    for (int k = 0; k < HID; ++k)
      s += (float)h8[0][b][k] * wl[k];
    out[(long)(r0 + b) * NCLS + j] = b_lin[j] + s * (1.f / 127.f);
  }
}

// ---------------------------------------------------------------------------
extern "C" void kernel_launch(void* const* d_in, const int* in_sizes, int n_in,
                              void* d_out, int out_size, void* d_ws, size_t ws_size,
                              hipStream_t stream)
{
  const int*   x     = (const int*)d_in[0];
  const float* emb   = (const float*)d_in[1];
  const float* w_ih  = (const float*)d_in[2];
  const float* w_hh  = (const float*)d_in[3];
  const float* b_ih  = (const float*)d_in[4];
  const float* b_hh  = (const float*)d_in[5];
  const float* w_lin = (const float*)d_in[6];
  const float* b_lin = (const float*)d_in[7];
  float*       out   = (float*)d_out;

  unsigned short* proj = (unsigned short*)d_ws;                  // 51.5 MB
  unsigned short* whi  = proj + (size_t)VOCAB * GATES;           // 64 KB
  unsigned short* wlo  = whi + (size_t)GATES * EMB;              // 64 KB

  wsplit_kernel<<<dim3((GATES * EMB + 255) / 256), dim3(256), 0, stream>>>(
      w_ih, whi, wlo);
  int vblocks = (VOCAB + 15) / 16;   // 3142
  emb_proj_kernel<<<dim3(vblocks), dim3(256), 0, stream>>>(
      emb, whi, wlo, b_ih, b_hh, proj);
  lstm_kernel<<<dim3(BATCH / 2), dim3(512), 0, stream>>>(
      x, w_hh, proj, w_lin, b_lin, out);
}